// Round 1
// baseline (548.510 us; speedup 1.0000x reference)
//
#include <hip/hip_runtime.h>

typedef unsigned int u32;
typedef unsigned long long u64;

// ---------------- workspace layout (bytes) ----------------
#define WS_WP2B 0        // u32 [64][3]
#define WS_WP2N 768
#define WS_WP3B 1536     // u32 [128][3][2]
#define WS_WP3N 4608
#define WS_WP4B 7680     // u32 [128][6][4]
#define WS_WP4N 19968
#define WS_SC1  32256    // float[32]
#define WS_SC2  32384    // float[64]
#define WS_SC3  32640    // float[128]
#define WS_SC4  33152    // float[128]
#define WS_TOTAL 33664

// ---------------- LDS layout (bytes) ----------------
#define OFF_XS  0        // int8 [6][136]  (pad 4 | 128 | pad 4)
#define OFF_SW1 832      // int8 [32][16]
#define OFF_S1B 1344     // u32 [6][34]
#define OFF_S1N 2160
#define OFF_S2B 2976     // u32 [6][34][2]
#define OFF_S2N 4608
#define OFF_S3B 6240     // u32 [6][16][4]
#define OFF_S3N 7776
#define OFF_H4  9312     // float [2048]
#define OFF_RED 17504    // float [40]
#define LDS_BYTES 17664

#define DEV __device__ __forceinline__

DEV void acc_word(u32 xb, u32 xn, u32 wb, u32 wn, int& na, int& nm) {
  u32 m = xn & wn;
  u32 d = (xb ^ wb) & m;
  na += __popc(m);
  nm += __popc(d);
}

DEV float bn_htanh_f(float y, float m, float sc, float be) {
  float t = (y - m) * sc + be;
  return fminf(1.0f, fmaxf(-1.0f, t));
}

// ---------------- setup: pack weight signs + BN scales into ws ----------------
__global__ void setup_pack(const float* __restrict__ w2, const float* __restrict__ w3,
                           const float* __restrict__ w4,
                           const float* __restrict__ g1, const float* __restrict__ v1,
                           const float* __restrict__ g2, const float* __restrict__ v2,
                           const float* __restrict__ g3, const float* __restrict__ v3,
                           const float* __restrict__ g4, const float* __restrict__ v4,
                           unsigned char* __restrict__ ws) {
  int t = blockIdx.x * 256 + threadIdx.x;
  if (t < 192) {                       // wp2: [c][k], 32 in-ch per word
    int c = t / 3, k = t % 3;
    u32 b = 0, n = 0;
    for (int ci = 0; ci < 32; ++ci) {
      float f = w2[(c * 32 + ci) * 3 + k];
      if (f < 0.0f) b |= 1u << ci;
      if (f != 0.0f) n |= 1u << ci;
    }
    ((u32*)(ws + WS_WP2B))[t] = b;
    ((u32*)(ws + WS_WP2N))[t] = n;
  } else if (t < 960) {                // wp3: [c][k][g] : (c*3+k)*2+g
    int i = t - 192;
    int g = i & 1, k = (i >> 1) % 3, c = i / 6;
    u32 b = 0, n = 0;
    for (int x = 0; x < 32; ++x) {
      int ci = g * 32 + x;
      float f = w3[(c * 64 + ci) * 3 + k];
      if (f < 0.0f) b |= 1u << x;
      if (f != 0.0f) n |= 1u << x;
    }
    ((u32*)(ws + WS_WP3B))[i] = b;
    ((u32*)(ws + WS_WP3N))[i] = n;
  } else if (t < 4032) {               // wp4: [c][r][g] : (c*6+r)*4+g
    int i = t - 960;
    int g = i & 3, r = (i >> 2) % 6, c = i / 24;
    u32 b = 0, n = 0;
    for (int x = 0; x < 32; ++x) {
      int ci = g * 32 + x;
      float f = w4[(c * 128 + ci) * 6 + r];
      if (f < 0.0f) b |= 1u << x;
      if (f != 0.0f) n |= 1u << x;
    }
    ((u32*)(ws + WS_WP4B))[i] = b;
    ((u32*)(ws + WS_WP4N))[i] = n;
  } else if (t < 4384) {               // BN scales
    int i = t - 4032;
    const float* g; const float* v; float* dst; int c;
    if (i < 32)       { g = g1; v = v1; dst = (float*)(ws + WS_SC1); c = i; }
    else if (i < 96)  { g = g2; v = v2; dst = (float*)(ws + WS_SC2); c = i - 32; }
    else if (i < 224) { g = g3; v = v3; dst = (float*)(ws + WS_SC3); c = i - 96; }
    else              { g = g4; v = v4; dst = (float*)(ws + WS_SC4); c = i - 224; }
    dst[c] = g[c] / sqrtf(v[c] + 1e-5f);
  }
}

// ---------------- fused network: one block per sample ----------------
__global__ __launch_bounds__(256, 4) void bnn_fused(
    const float* __restrict__ x,  const float* __restrict__ w1,
    const float* __restrict__ b1, const float* __restrict__ m1, const float* __restrict__ be1,
    const float* __restrict__ b2, const float* __restrict__ m2, const float* __restrict__ be2,
    const float* __restrict__ b3, const float* __restrict__ m3, const float* __restrict__ be3,
    const float* __restrict__ b4, const float* __restrict__ m4, const float* __restrict__ be4,
    const float* __restrict__ wfc, const float* __restrict__ bfc,
    const unsigned char* __restrict__ ws, float* __restrict__ out) {
  __shared__ __align__(16) unsigned char L[LDS_BYTES];
  const int t = threadIdx.x;
  const int n = blockIdx.x;
  const int lane = t & 63;

  // ---- init: zero [0, OFF_S2N end) = xs, sw1, s1b/n, s2b/n (pads rely on this) ----
  for (int i = t; i < 6240 / 4; i += 256) ((u32*)L)[i] = 0u;
  __syncthreads();

  // ---- load x signs (int8) and w1 signs (int8) ----
  for (int i = t; i < 768; i += 256) {
    int r = i >> 7, w = i & 127;
    float v = x[n * 768 + i];
    ((signed char*)L)[OFF_XS + r * 136 + 4 + w] = (signed char)((v > 0.0f) - (v < 0.0f));
  }
  for (int i = t; i < 288; i += 256) {
    float v = w1[i];
    int c = i / 9, k = i - c * 9;
    ((signed char*)L)[OFF_SW1 + c * 16 + k] = (signed char)((v > 0.0f) - (v < 0.0f));
  }
  __syncthreads();

  // ---- Phase A: L1 conv(1x9,s2,p4) + BN + htanh + pool(1x2) + sign -> s1 bits ----
  {
    const int q = t >> 5;        // position group 0..7 (half-wave)
    const int c = t & 31;        // out channel 0..31
    const float b1c = b1[c], m1c = m1[c], be1c = be1[c];
    const float sc1c = ((const float*)(ws + WS_SC1))[c];
    int w1s[9];
#pragma unroll
    for (int k = 0; k < 9; ++k) w1s[k] = ((const signed char*)L)[OFF_SW1 + c * 16 + k];
    for (int i = 0; i < 24; ++i) {
      int pos = q * 24 + i;              // 192 pooled positions: r in [0,6), j in [0,32)
      int r = pos >> 5, j = pos & 31;
      const signed char* xp = (const signed char*)L + OFF_XS + r * 136 + 4 * j;
      int xv[11];
#pragma unroll
      for (int u = 0; u < 11; ++u) xv[u] = xp[u];
      int a0 = 0, a1 = 0;
#pragma unroll
      for (int k = 0; k < 9; ++k) { a0 += xv[k] * w1s[k]; a1 += xv[k + 2] * w1s[k]; }
      float t0 = bn_htanh_f((float)a0 + b1c, m1c, sc1c, be1c);
      float t1 = bn_htanh_f((float)a1 + b1c, m1c, sc1c, be1c);
      float tm = fmaxf(t0, t1);
      u64 bb = __ballot(tm < 0.0f);
      u64 nn = __ballot(tm != 0.0f);
      if (lane == 0) {
        ((u32*)(L + OFF_S1B))[r * 34 + j + 1] = (u32)bb;
        ((u32*)(L + OFF_S1N))[r * 34 + j + 1] = (u32)nn;
      } else if (lane == 32) {
        ((u32*)(L + OFF_S1B))[r * 34 + j + 1] = (u32)(bb >> 32);
        ((u32*)(L + OFF_S1N))[r * 34 + j + 1] = (u32)(nn >> 32);
      }
    }
  }
  __syncthreads();

  // ---- Phase B: L2 conv(1x3,p1) + BN + htanh + sign -> s2 bits ----
  {
    const int wave = t >> 6;     // 0..3, one position per wave per iter
    const int c = lane;          // out channel 0..63
    const float b2c = b2[c], m2c = m2[c], be2c = be2[c];
    const float sc2c = ((const float*)(ws + WS_SC2))[c];
    u32 wb[3], wn[3];
#pragma unroll
    for (int k = 0; k < 3; ++k) {
      wb[k] = ((const u32*)(ws + WS_WP2B))[c * 3 + k];
      wn[k] = ((const u32*)(ws + WS_WP2N))[c * 3 + k];
    }
    const u32* s1b = (const u32*)(L + OFF_S1B);
    const u32* s1n = (const u32*)(L + OFF_S1N);
    for (int i = 0; i < 48; ++i) {
      int pos = wave * 48 + i;           // 192 positions: r in [0,6), w in [0,32)
      int r = pos >> 5, w = pos & 31;
      int na = 0, nm = 0;
#pragma unroll
      for (int k = 0; k < 3; ++k)
        acc_word(s1b[r * 34 + w + k], s1n[r * 34 + w + k], wb[k], wn[k], na, nm);
      float tv = bn_htanh_f((float)(na - 2 * nm) + b2c, m2c, sc2c, be2c);
      u64 bb = __ballot(tv < 0.0f);
      u64 nn = __ballot(tv != 0.0f);
      if (lane == 0) {
        u32* p  = (u32*)(L + OFF_S2B) + (r * 34 + w + 1) * 2;
        u32* pn = (u32*)(L + OFF_S2N) + (r * 34 + w + 1) * 2;
        p[0] = (u32)bb;  p[1] = (u32)(bb >> 32);
        pn[0] = (u32)nn; pn[1] = (u32)(nn >> 32);
      }
    }
  }
  __syncthreads();

  // ---- Phase C: L3 conv(1x3,p1) + BN + htanh + pool(1x2) + sign -> s3 bits ----
  {
    const int wave = t >> 6;
    u32 wb[2][3][2], wn[2][3][2];
    float b3c[2], m3c[2], be3c[2], sc3c[2];
#pragma unroll
    for (int h = 0; h < 2; ++h) {
      int c = h * 64 + lane;
      b3c[h] = b3[c]; m3c[h] = m3[c]; be3c[h] = be3[c];
      sc3c[h] = ((const float*)(ws + WS_SC3))[c];
#pragma unroll
      for (int k = 0; k < 3; ++k) {
        uint2 vb = *(const uint2*)((const u32*)(ws + WS_WP3B) + (c * 3 + k) * 2);
        uint2 vn = *(const uint2*)((const u32*)(ws + WS_WP3N) + (c * 3 + k) * 2);
        wb[h][k][0] = vb.x; wb[h][k][1] = vb.y;
        wn[h][k][0] = vn.x; wn[h][k][1] = vn.y;
      }
    }
    const u32* s2b = (const u32*)(L + OFF_S2B);
    const u32* s2n = (const u32*)(L + OFF_S2N);
    for (int i = 0; i < 24; ++i) {
      int pos = wave * 24 + i;           // 96 pooled positions: r in [0,6), j in [0,16)
      int r = pos >> 4, j = pos & 15;
      u32 xb[4][2], xn[4][2];
#pragma unroll
      for (int col = 0; col < 4; ++col) {
        int base = (r * 34 + 2 * j + col) * 2;
        uint2 vb = *(const uint2*)(s2b + base);
        uint2 vn = *(const uint2*)(s2n + base);
        xb[col][0] = vb.x; xb[col][1] = vb.y;
        xn[col][0] = vn.x; xn[col][1] = vn.y;
      }
#pragma unroll
      for (int h = 0; h < 2; ++h) {
        int na0 = 0, nm0 = 0, na1 = 0, nm1 = 0;
#pragma unroll
        for (int col = 0; col < 4; ++col) {
#pragma unroll
          for (int g = 0; g < 2; ++g) {
            if (col < 3) acc_word(xb[col][g], xn[col][g], wb[h][col][g], wn[h][col][g], na0, nm0);
            if (col > 0) acc_word(xb[col][g], xn[col][g], wb[h][col - 1][g], wn[h][col - 1][g], na1, nm1);
          }
        }
        float t0 = bn_htanh_f((float)(na0 - 2 * nm0) + b3c[h], m3c[h], sc3c[h], be3c[h]);
        float t1 = bn_htanh_f((float)(na1 - 2 * nm1) + b3c[h], m3c[h], sc3c[h], be3c[h]);
        float tm = fmaxf(t0, t1);
        u64 bb = __ballot(tm < 0.0f);
        u64 nn = __ballot(tm != 0.0f);
        if (lane == 0) {
          u32* p  = (u32*)(L + OFF_S3B) + (r * 16 + j) * 4 + h * 2;
          u32* pn = (u32*)(L + OFF_S3N) + (r * 16 + j) * 4 + h * 2;
          p[0] = (u32)bb;  p[1] = (u32)(bb >> 32);
          pn[0] = (u32)nn; pn[1] = (u32)(nn >> 32);
        }
      }
    }
  }
  __syncthreads();

  // ---- Phase D: L4 conv(6x1, full-height) + BN + htanh -> h4 (float) ----
  {
    const int c = t >> 1, q8 = (t & 1) * 8;
    const float b4c = b4[c], m4c = m4[c], be4c = be4[c];
    const float sc4c = ((const float*)(ws + WS_SC4))[c];
    int na[8], nm[8];
#pragma unroll
    for (int wi = 0; wi < 8; ++wi) { na[wi] = 0; nm[wi] = 0; }
    const u32* s3b = (const u32*)(L + OFF_S3B);
    const u32* s3n = (const u32*)(L + OFF_S3N);
#pragma unroll
    for (int r = 0; r < 6; ++r) {
      uint4 wbv = *(const uint4*)((const u32*)(ws + WS_WP4B) + (c * 6 + r) * 4);
      uint4 wnv = *(const uint4*)((const u32*)(ws + WS_WP4N) + (c * 6 + r) * 4);
#pragma unroll
      for (int wi = 0; wi < 8; ++wi) {
        int w = q8 + wi;
        uint4 xbv = *(const uint4*)(s3b + (r * 16 + w) * 4);
        uint4 xnv = *(const uint4*)(s3n + (r * 16 + w) * 4);
        acc_word(xbv.x, xnv.x, wbv.x, wnv.x, na[wi], nm[wi]);
        acc_word(xbv.y, xnv.y, wbv.y, wnv.y, na[wi], nm[wi]);
        acc_word(xbv.z, xnv.z, wbv.z, wnv.z, na[wi], nm[wi]);
        acc_word(xbv.w, xnv.w, wbv.w, wnv.w, na[wi], nm[wi]);
      }
    }
#pragma unroll
    for (int wi = 0; wi < 8; ++wi) {
      float tv = bn_htanh_f((float)(na[wi] - 2 * nm[wi]) + b4c, m4c, sc4c, be4c);
      ((float*)(L + OFF_H4))[c * 16 + q8 + wi] = tv;
    }
  }
  __syncthreads();

  // ---- Phase E: FC (2048 -> 10) ----
  {
    const float* h4 = (const float*)(L + OFF_H4);
    float xv[8];
#pragma unroll
    for (int u = 0; u < 8; ++u) xv[u] = h4[t * 8 + u];
    float part[10];
#pragma unroll
    for (int o = 0; o < 10; ++o) {
      const float* wr = wfc + o * 2048 + t * 8;
      float s = 0.0f;
#pragma unroll
      for (int u = 0; u < 8; ++u) s += xv[u] * wr[u];
      part[o] = s;
    }
#pragma unroll
    for (int o = 0; o < 10; ++o) {
      float v = part[o];
#pragma unroll
      for (int s = 32; s >= 1; s >>= 1) v += __shfl_down(v, s, 64);
      part[o] = v;
    }
    const int wave = t >> 6;
    if (lane == 0) {
#pragma unroll
      for (int o = 0; o < 10; ++o) ((float*)(L + OFF_RED))[wave * 10 + o] = part[o];
    }
  }
  __syncthreads();
  if (t < 10) {
    const float* red = (const float*)(L + OFF_RED);
    out[n * 10 + t] = red[t] + red[10 + t] + red[20 + t] + red[30 + t] + bfc[t];
  }
}

extern "C" void kernel_launch(void* const* d_in, const int* in_sizes, int n_in,
                              void* d_out, int out_size, void* d_ws, size_t ws_size,
                              hipStream_t stream) {
  const float* x   = (const float*)d_in[0];
  const float* w1  = (const float*)d_in[1];
  const float* w2  = (const float*)d_in[2];
  const float* w3  = (const float*)d_in[3];
  const float* w4  = (const float*)d_in[4];
  const float* b1  = (const float*)d_in[5];
  const float* g1  = (const float*)d_in[6];
  const float* be1 = (const float*)d_in[7];
  const float* m1  = (const float*)d_in[8];
  const float* v1  = (const float*)d_in[9];
  const float* b2  = (const float*)d_in[10];
  const float* g2  = (const float*)d_in[11];
  const float* be2 = (const float*)d_in[12];
  const float* m2  = (const float*)d_in[13];
  const float* v2  = (const float*)d_in[14];
  const float* b3  = (const float*)d_in[15];
  const float* g3  = (const float*)d_in[16];
  const float* be3 = (const float*)d_in[17];
  const float* m3  = (const float*)d_in[18];
  const float* v3  = (const float*)d_in[19];
  const float* b4  = (const float*)d_in[20];
  const float* g4  = (const float*)d_in[21];
  const float* be4 = (const float*)d_in[22];
  const float* m4  = (const float*)d_in[23];
  const float* v4  = (const float*)d_in[24];
  const float* wfc = (const float*)d_in[25];
  const float* bfc = (const float*)d_in[26];
  unsigned char* ws = (unsigned char*)d_ws;
  float* out = (float*)d_out;

  const int N = in_sizes[0] / 768;   // 8192 samples

  setup_pack<<<18, 256, 0, stream>>>(w2, w3, w4, g1, v1, g2, v2, g3, v3, g4, v4, ws);
  bnn_fused<<<N, 256, 0, stream>>>(x, w1, b1, m1, be1, b2, m2, be2,
                                   b3, m3, be3, b4, m4, be4, wfc, bfc, ws, out);
}